// Round 3
// baseline (464.507 us; speedup 1.0000x reference)
//
#include <hip/hip_runtime.h>
#include <math.h>

#define NF 8
#define NQ 300
#define HSZ 96
#define WSZ 96
#define HW 9216
#define DTOT 73728
#define NT 256
#define NBF 16

// ws float offsets
#define WS_TGTY 0        // [16][96] max over h
#define WS_TGTX 1536     // [16][96] max over w
#define WS_TSUM 3072     // [16]
#define WS_YSUM 3088     // [16]
#define WS_XSUM 3104     // [16]
#define WS_TBITS 3200    // 16 planes * 288 u32 (tmask bits)
#define WS_PBITS 7808    // 2 planes * 288 u32 (vpad bits)
#define WS_PART  8448    // [4800][8] partials

__device__ __forceinline__ float sigmoid_fast(float x) {
    float e = __expf(-fabsf(x));
    float inv = __builtin_amdgcn_rcpf(1.f + e);
    return x >= 0.f ? inv : e * inv;
}

// one block per (b,f): target projections/sums + bit-pack tmask (and vpad for 2 blocks)
__global__ __launch_bounds__(NT)
void targets_kernel(const float* __restrict__ tm, const unsigned char* __restrict__ vpad,
                    float* __restrict__ ws) {
    int bf = blockIdx.x, t = threadIdx.x;
    int lane = t & 63, wv = t >> 6;
    __shared__ float tile[HSZ * 97];
    __shared__ float red[4][4];
    unsigned long long* tb64 = (unsigned long long*)(ws + WS_TBITS) + bf * 144;
    const float* base = tm + (size_t)bf * HW;
    float tsum = 0.f;
    #pragma unroll
    for (int it = 0; it < 36; ++it) {
        int e = it * NT + t;
        float v = base[e];
        tsum += v;
        unsigned long long bt = __ballot(v != 0.f);
        if (lane == 0) tb64[it * 4 + wv] = bt;
        tile[e + e / 96] = v;        // stride-97 padded
    }
    if ((bf & 7) == 0) {             // pack vpad plane b (block-uniform branch)
        int b = bf >> 3;
        unsigned long long* pb64 = (unsigned long long*)(ws + WS_PBITS) + b * 144;
        const unsigned char* pp = vpad + (size_t)b * HW;
        #pragma unroll
        for (int it = 0; it < 36; ++it) {
            int e = it * NT + t;
            unsigned long long bt = __ballot(pp[e] != 0);
            if (lane == 0) pb64[it * 4 + wv] = bt;
        }
    }
    __syncthreads();
    float ysum = 0.f, xsum = 0.f;
    if (t < 96) {
        float m = -INFINITY;
        #pragma unroll 8
        for (int h = 0; h < HSZ; ++h) m = fmaxf(m, tile[h * 97 + t]);
        ws[WS_TGTY + bf * 96 + t] = m;
        ysum = m;
    } else if (t < 192) {
        int hh = t - 96;
        float m = -INFINITY;
        #pragma unroll 8
        for (int w = 0; w < WSZ; ++w) m = fmaxf(m, tile[hh * 97 + w]);
        ws[WS_TGTX + bf * 96 + hh] = m;
        xsum = m;
    }
    float v0 = tsum, v1 = ysum, v2 = xsum;
    #pragma unroll
    for (int off = 32; off > 0; off >>= 1) {
        v0 += __shfl_down(v0, off, 64);
        v1 += __shfl_down(v1, off, 64);
        v2 += __shfl_down(v2, off, 64);
    }
    if (lane == 0) { red[wv][0] = v0; red[wv][1] = v1; red[wv][2] = v2; }
    __syncthreads();
    if (t == 0) {
        #pragma unroll
        for (int w = 1; w < 4; ++w) { v0 += red[w][0]; v1 += red[w][1]; v2 += red[w][2]; }
        ws[WS_TSUM + bf] = v0;
        ws[WS_YSUM + bf] = v1;
        ws[WS_XSUM + bf] = v2;
    }
}

// one block per (b,f,q): focal/dice/projection partials over one 96x96 plane
__global__ __launch_bounds__(NT, 8)
void partial_kernel(const float* __restrict__ masks, const float* __restrict__ ws,
                    float* __restrict__ part) {
    int blk = blockIdx.x;
    int bf = blk / NQ;
    int q  = blk - bf * NQ;
    int b  = bf >> 3;
    int t  = threadIdx.x;

    __shared__ unsigned short tile[HSZ * 98];   // bf16 (truncated), stride-98
    __shared__ float red[4][8];

    const float4* mrow = (const float4*)(masks + (size_t)(bf * NQ + q) * HW);
    const unsigned* tb = (const unsigned*)(ws + WS_TBITS) + bf * 288;
    const unsigned* pb = (const unsigned*)(ws + WS_PBITS) + b * 288;

    // deep prefetch of the only big stream
    float4 xv[9];
    #pragma unroll
    for (int it = 0; it < 9; ++it) xv[it] = mrow[it * NT + t];

    int widx = t >> 3;               // word sub-index, + it*32 per iter
    int sh = (t & 7) * 4;            // nibble shift, constant across iters

    float focal = 0.f, dnum = 0.f, dden = 0.f;

    #pragma unroll
    for (int it = 0; it < 9; ++it) {
        int i4 = it * NT + t;
        unsigned tw = tb[it * 32 + widx] >> sh;
        unsigned pw = pb[it * 32 + widx] >> sh;
        int h = i4 / 24;
        int c = (i4 - h * 24) * 4;

        float xs[4] = {xv[it].x, xv[it].y, xv[it].z, xv[it].w};
        unsigned us[4];
        #pragma unroll
        for (int j = 0; j < 4; ++j) {
            float x = ((pw >> j) & 1u) ? 0.f : xs[j];
            float tg = (float)((tw >> j) & 1u);
            float ee = __expf(-fabsf(x));
            float se = 1.f + ee;
            float inv = __builtin_amdgcn_rcpf(se);
            float s = x >= 0.f ? inv : ee * inv;          // sigmoid(x)
            float L = __logf(se);                          // log1p(exp(-|x|))
            float ce = fmaxf(x, 0.f) - x * tg + L;
            float omp = s + tg - 2.f * s * tg;             // 1 - p_t
            float at = 0.75f - 0.5f * tg;                  // alpha_t
            focal = fmaf(at * ce, omp * omp, focal);
            dnum = fmaf(s, tg, dnum);
            dden += s;
            us[j] = __float_as_uint(x) >> 16;              // bf16 trunc (monotone)
        }
        int ta = h * 98 + c;                               // even
        *(unsigned*)&tile[ta]     = us[0] | (us[1] << 16);
        *(unsigned*)&tile[ta + 2] = us[2] | (us[3] << 16);
    }
    __syncthreads();

    float pYn = 0.f, pYd = 0.f, pXn = 0.f, pXd = 0.f;
    if (t < 96) {
        float m = -INFINITY;
        #pragma unroll 8
        for (int h = 0; h < HSZ; ++h)
            m = fmaxf(m, __uint_as_float((unsigned)tile[h * 98 + t] << 16));
        float sg = sigmoid_fast(m);
        pYd = sg;
        pYn = sg * ws[WS_TGTY + bf * 96 + t];
    } else if (t < 192) {
        int hh = t - 96;
        float m = -INFINITY;
        #pragma unroll 8
        for (int w = 0; w < WSZ; ++w)
            m = fmaxf(m, __uint_as_float((unsigned)tile[hh * 98 + w] << 16));
        float sg = sigmoid_fast(m);
        pXd = sg;
        pXn = sg * ws[WS_TGTX + bf * 96 + hh];
    }

    // single-barrier 7-way block reduction
    float v[7] = {focal, dnum, dden, pYn, pYd, pXn, pXd};
    #pragma unroll
    for (int k = 0; k < 7; ++k)
        #pragma unroll
        for (int off = 32; off > 0; off >>= 1) v[k] += __shfl_down(v[k], off, 64);
    int wv = t >> 6, lane = t & 63;
    if (lane == 0) {
        #pragma unroll
        for (int k = 0; k < 7; ++k) red[wv][k] = v[k];
    }
    __syncthreads();
    if (t == 0) {
        #pragma unroll
        for (int w = 1; w < 4; ++w)
            #pragma unroll
            for (int k = 0; k < 7; ++k) v[k] += red[w][k];
        float4* p = (float4*)(part + (size_t)blk * 8);
        p[0] = make_float4(v[0], v[1], v[2], v[3]);
        p[1] = make_float4(v[4], v[5], v[6], 0.f);
    }
}

// grid=2 (one block per b): combine partials + class/bbox/giou, then argmin
__global__ __launch_bounds__(NT)
void final_kernel(const float* __restrict__ logits, const float* __restrict__ boxes,
                  const float* __restrict__ tbox, const int* __restrict__ tvalid,
                  const float* __restrict__ ws, float* __restrict__ out, int write_idx) {
    int b = blockIdx.x, t = threadIdx.x;
    const float* part = ws + WS_PART;

    float best = INFINITY;
    int bi = 0x7fffffff;

    for (int q = t; q < NQ; q += NT) {
        float focal = 0.f, dnum = 0.f, dden = 0.f;
        float pYn = 0.f, pYd = 0.f, pXn = 0.f, pXd = 0.f;
        float tsum = 0.f, ysum = 0.f, xsum = 0.f;
        #pragma unroll
        for (int f = 0; f < NF; ++f) {
            int bf = b * NF + f;
            const float4* p = (const float4*)(part + (size_t)(bf * NQ + q) * 8);
            float4 pa = p[0], pbv = p[1];
            focal += pa.x; dnum += pa.y; dden += pa.z; pYn += pa.w;
            pYd += pbv.x; pXn += pbv.y; pXd += pbv.z;
            tsum += ws[WS_TSUM + bf];
            ysum += ws[WS_YSUM + bf];
            xsum += ws[WS_XSUM + bf];
        }
        float cost_mask = focal / (float)DTOT;
        float cost_dice = -(2.f * dnum + 1.f) / (dden + tsum + 1.f);
        float coefY = (2.f * pYn + 1.f) / (pYd + ysum + 1.f);
        float coefX = (2.f * pXn + 1.f) / (pXd + xsum + 1.f);
        float cost_proj = -0.5f * (coefY + coefX);

        float wsum = 0.f, cls = 0.f, cb = 0.f, cg = 0.f;
        #pragma unroll
        for (int f = 0; f < NF; ++f) {
            float wv = (tvalid[b * NF + f] != 0) ? 1.f : 0.f;
            wsum += wv;
            float lg = logits[(b * NF + f) * NQ + q];
            float p = sigmoid_fast(lg);
            float negc = 0.75f * p * p * (-__logf(1.f - p + 1e-8f));
            float posc = 0.25f * (1.f - p) * (1.f - p) * (-__logf(p + 1e-8f));
            cls += (posc - negc) * wv;

            const float* bx = boxes + (size_t)((b * NF + f) * NQ + q) * 4;
            const float* tbp = tbox + (b * NF + f) * 4;
            float cx = bx[0], cy = bx[1], bw = bx[2], bh = bx[3];
            float tcx = tbp[0], tcy = tbp[1], tbw = tbp[2], tbh = tbp[3];
            cb += fabsf(cx - tcx) + fabsf(cy - tcy) + fabsf(bw - tbw) + fabsf(bh - tbh);
            float sx1 = cx - 0.5f * bw, sy1 = cy - 0.5f * bh;
            float sx2 = cx + 0.5f * bw, sy2 = cy + 0.5f * bh;
            float tx1 = tcx - 0.5f * tbw, ty1 = tcy - 0.5f * tbh;
            float tx2 = tcx + 0.5f * tbw, ty2 = tcy + 0.5f * tbh;
            float a1 = (sx2 - sx1) * (sy2 - sy1), a2 = (tx2 - tx1) * (ty2 - ty1);
            float iw = fmaxf(fminf(sx2, tx2) - fmaxf(sx1, tx1), 0.f);
            float ih = fmaxf(fminf(sy2, ty2) - fmaxf(sy1, ty1), 0.f);
            float inter = iw * ih;
            float uni = a1 + a2 - inter;
            float iou = inter / uni;
            float cw = fmaxf(fmaxf(sx2, tx2) - fminf(sx1, tx1), 0.f);
            float chh = fmaxf(fmaxf(sy2, ty2) - fminf(sy1, ty1), 0.f);
            float areac = cw * chh;
            cg += -(iou - (areac - uni) / areac);
        }
        cls /= wsum;
        float c = cls + 0.125f * cb + 0.125f * cg + cost_mask + cost_dice + cost_proj;
        out[b * NQ + q] = c;
        if (c < best) { best = c; bi = q; }
    }

    #pragma unroll
    for (int off = 32; off > 0; off >>= 1) {
        float ov = __shfl_down(best, off, 64);
        int oi = __shfl_down(bi, off, 64);
        if (ov < best || (ov == best && oi < bi)) { best = ov; bi = oi; }
    }
    __shared__ float rv[4];
    __shared__ int ri[4];
    int wv = t >> 6, lane = t & 63;
    if (lane == 0) { rv[wv] = best; ri[wv] = bi; }
    __syncthreads();
    if (t == 0 && write_idx) {
        #pragma unroll
        for (int w = 1; w < 4; ++w) {
            if (rv[w] < best || (rv[w] == best && ri[w] < bi)) { best = rv[w]; bi = ri[w]; }
        }
        out[2 * NQ + b] = (float)bi;       // src_ind
        out[2 * NQ + 2 + b] = 0.f;         // tgt_ind
    }
}

extern "C" void kernel_launch(void* const* d_in, const int* in_sizes, int n_in,
                              void* d_out, int out_size, void* d_ws, size_t ws_size,
                              hipStream_t stream) {
    const float* logits = (const float*)d_in[0];
    const float* boxes  = (const float*)d_in[1];
    const float* masks  = (const float*)d_in[2];
    const float* tmask  = (const float*)d_in[3];
    const float* tbox   = (const float*)d_in[4];
    const int*   tvalid = (const int*)d_in[5];
    const unsigned char* vpad = (const unsigned char*)d_in[6];
    float* out = (float*)d_out;
    float* ws  = (float*)d_ws;

    targets_kernel<<<NBF, NT, 0, stream>>>(tmask, vpad, ws);
    partial_kernel<<<NBF * NQ, NT, 0, stream>>>(masks, ws, ws + WS_PART);
    int write_idx = (out_size >= 2 * NQ + 4) ? 1 : 0;
    final_kernel<<<2, NT, 0, stream>>>(logits, boxes, tbox, tvalid, ws, out, write_idx);
}

// Round 4
// 345.566 us; speedup vs baseline: 1.3442x; 1.3442x over previous
//
#include <hip/hip_runtime.h>
#include <math.h>

#define NF 8
#define NQ 300
#define HSZ 96
#define WSZ 96
#define HW 9216
#define DTOT 73728
#define NT 256
#define NBF 16

// ws float offsets
#define WS_TGTY 0        // [16][96] max over h
#define WS_TGTX 1536     // [16][96] max over w
#define WS_TSUM 3072     // [16]
#define WS_YSUM 3088     // [16]
#define WS_XSUM 3104     // [16]
#define WS_TBITS 3200    // 16 planes * 288 u32 (tmask bits)
#define WS_PBITS 7808    // 2 planes * 288 u32 (vpad bits)
#define WS_PART  8448    // [4800][8] partials

__device__ __forceinline__ float sigmoid_fast(float x) {
    float e = __expf(-fabsf(x));
    float inv = __builtin_amdgcn_rcpf(1.f + e);
    return x >= 0.f ? inv : e * inv;
}

__device__ __forceinline__ float bf16tof(unsigned short u) {
    return __uint_as_float((unsigned)u << 16);
}

// one block per (b,f): target projections/sums + bit-pack tmask (and vpad for 2 blocks)
__global__ __launch_bounds__(NT)
void targets_kernel(const float* __restrict__ tm, const unsigned char* __restrict__ vpad,
                    float* __restrict__ ws) {
    int bf = blockIdx.x, t = threadIdx.x;
    int lane = t & 63, wv = t >> 6;
    __shared__ float tile[HSZ * 97];
    __shared__ float red[4][4];
    unsigned long long* tb64 = (unsigned long long*)(ws + WS_TBITS) + bf * 144;
    const float* base = tm + (size_t)bf * HW;
    float tsum = 0.f;
    #pragma unroll
    for (int it = 0; it < 36; ++it) {
        int e = it * NT + t;
        float v = base[e];
        tsum += v;
        unsigned long long bt = __ballot(v != 0.f);
        if (lane == 0) tb64[it * 4 + wv] = bt;
        tile[e + e / 96] = v;        // stride-97 padded
    }
    if ((bf & 7) == 0) {             // pack vpad plane b (block-uniform branch)
        int b = bf >> 3;
        unsigned long long* pb64 = (unsigned long long*)(ws + WS_PBITS) + b * 144;
        const unsigned char* pp = vpad + (size_t)b * HW;
        #pragma unroll
        for (int it = 0; it < 36; ++it) {
            int e = it * NT + t;
            unsigned long long bt = __ballot(pp[e] != 0);
            if (lane == 0) pb64[it * 4 + wv] = bt;
        }
    }
    __syncthreads();
    float ysum = 0.f, xsum = 0.f;
    if (t < 96) {
        float m = -INFINITY;
        #pragma unroll 8
        for (int h = 0; h < HSZ; ++h) m = fmaxf(m, tile[h * 97 + t]);
        ws[WS_TGTY + bf * 96 + t] = m;
        ysum = m;
    } else if (t < 192) {
        int hh = t - 96;
        float m = -INFINITY;
        #pragma unroll 8
        for (int w = 0; w < WSZ; ++w) m = fmaxf(m, tile[hh * 97 + w]);
        ws[WS_TGTX + bf * 96 + hh] = m;
        xsum = m;
    }
    float v0 = tsum, v1 = ysum, v2 = xsum;
    #pragma unroll
    for (int off = 32; off > 0; off >>= 1) {
        v0 += __shfl_down(v0, off, 64);
        v1 += __shfl_down(v1, off, 64);
        v2 += __shfl_down(v2, off, 64);
    }
    if (lane == 0) { red[wv][0] = v0; red[wv][1] = v1; red[wv][2] = v2; }
    __syncthreads();
    if (t == 0) {
        #pragma unroll
        for (int w = 1; w < 4; ++w) { v0 += red[w][0]; v1 += red[w][1]; v2 += red[w][2]; }
        ws[WS_TSUM + bf] = v0;
        ws[WS_YSUM + bf] = v1;
        ws[WS_XSUM + bf] = v2;
    }
}

// one block per (b,f,q): focal/dice/projection partials over one 96x96 plane
__global__ __launch_bounds__(NT, 8)
void partial_kernel(const float* __restrict__ masks, const float* __restrict__ ws,
                    float* __restrict__ part) {
    int blk = blockIdx.x;
    int bf = blk / NQ;
    int q  = blk - bf * NQ;
    int b  = bf >> 3;
    int t  = threadIdx.x;

    __shared__ unsigned short tile[HSZ * 98];   // bf16 (truncated), stride-98
    __shared__ float scratch[384];              // proj halves, reused for reduction

    const float4* mrow = (const float4*)(masks + (size_t)(bf * NQ + q) * HW);
    const unsigned* tb = (const unsigned*)(ws + WS_TBITS) + bf * 288;
    const unsigned* pb = (const unsigned*)(ws + WS_PBITS) + b * 288;

    int widx = t >> 3;               // shared dword index
    int sh = (t & 7) * 4;            // nibble shift

    // 1-deep rolling prefetch (fits in 64-VGPR cap; 9-deep spilled in R3)
    float4 cur = mrow[t];
    unsigned twc = tb[widx] >> sh;
    unsigned pwc = pb[widx] >> sh;

    float focal = 0.f, dnum = 0.f, dden = 0.f;

    #pragma unroll
    for (int it = 0; it < 9; ++it) {
        float4 nxt = cur;
        unsigned twn = 0u, pwn = 0u;
        if (it < 8) {
            nxt = mrow[(it + 1) * NT + t];
            twn = tb[(it + 1) * 32 + widx] >> sh;
            pwn = pb[(it + 1) * 32 + widx] >> sh;
        }
        int i4 = it * NT + t;
        int h = i4 / 24;
        int c = (i4 - h * 24) * 4;

        float xs[4] = {cur.x, cur.y, cur.z, cur.w};
        if (pwc & 0xFu) {                         // execz-skipped when no padding
            #pragma unroll
            for (int j = 0; j < 4; ++j)
                if ((pwc >> j) & 1u) xs[j] = 0.f;
        }
        unsigned us[4];
        #pragma unroll
        for (int j = 0; j < 4; ++j) {
            float x = xs[j];
            float tg = (float)((twc >> j) & 1u);
            float ee = __expf(-fabsf(x));
            float se = 1.f + ee;
            float inv = __builtin_amdgcn_rcpf(se);
            float s = x >= 0.f ? inv : ee * inv;          // sigmoid(x)
            float L = __logf(se);                          // log1p(exp(-|x|))
            float ce = fmaxf(x, 0.f) - x * tg + L;
            float omp = s + tg - 2.f * s * tg;             // 1 - p_t
            float at = 0.75f - 0.5f * tg;                  // alpha_t
            focal = fmaf(at * ce, omp * omp, focal);
            dnum = fmaf(s, tg, dnum);
            dden += s;
            us[j] = __float_as_uint(x) >> 16;              // bf16 trunc (monotone)
        }
        int ta = h * 98 + c;                               // even
        *(unsigned*)&tile[ta]     = us[0] | (us[1] << 16);
        *(unsigned*)&tile[ta + 2] = us[2] | (us[3] << 16);
        cur = nxt; twc = twn; pwc = pwn;
    }
    __syncthreads();

    // projection: 48-deep halves over 192 threads (halves tail critical path)
    if (t < 192) {
        int half = t / 96;
        int u = t - half * 96;
        int k0 = half * 48;
        float mc = -INFINITY, mr = -INFINITY;
        #pragma unroll 4
        for (int k = 0; k < 48; ++k) {
            mc = fmaxf(mc, bf16tof(tile[(k0 + k) * 98 + u]));   // col u
            mr = fmaxf(mr, bf16tof(tile[u * 98 + (k0 + k)]));   // row u
        }
        scratch[half * 96 + u] = mc;
        scratch[192 + half * 96 + u] = mr;
    }
    __syncthreads();

    float pYn = 0.f, pYd = 0.f, pXn = 0.f, pXd = 0.f;
    if (t < 96) {
        float m = fmaxf(scratch[t], scratch[96 + t]);
        float sg = sigmoid_fast(m);
        pYd = sg;
        pYn = sg * ws[WS_TGTY + bf * 96 + t];
    } else if (t < 192) {
        int r = t - 96;
        float m = fmaxf(scratch[192 + r], scratch[288 + r]);
        float sg = sigmoid_fast(m);
        pXd = sg;
        pXn = sg * ws[WS_TGTX + bf * 96 + r];
    }
    __syncthreads();                 // scratch reads done; reuse for reduction

    float v[7] = {focal, dnum, dden, pYn, pYd, pXn, pXd};
    #pragma unroll
    for (int k = 0; k < 7; ++k)
        #pragma unroll
        for (int off = 32; off > 0; off >>= 1) v[k] += __shfl_down(v[k], off, 64);
    int wv = t >> 6, lane = t & 63;
    if (lane == 0) {
        #pragma unroll
        for (int k = 0; k < 7; ++k) scratch[wv * 8 + k] = v[k];
    }
    __syncthreads();
    if (t == 0) {
        #pragma unroll
        for (int w = 1; w < 4; ++w)
            #pragma unroll
            for (int k = 0; k < 7; ++k) v[k] += scratch[w * 8 + k];
        float4* p = (float4*)(part + (size_t)blk * 8);
        p[0] = make_float4(v[0], v[1], v[2], v[3]);
        p[1] = make_float4(v[4], v[5], v[6], 0.f);
    }
}

// grid=2 (one block per b): combine partials + class/bbox/giou, then argmin
__global__ __launch_bounds__(NT)
void final_kernel(const float* __restrict__ logits, const float* __restrict__ boxes,
                  const float* __restrict__ tbox, const int* __restrict__ tvalid,
                  const float* __restrict__ ws, float* __restrict__ out, int write_idx) {
    int b = blockIdx.x, t = threadIdx.x;
    const float* part = ws + WS_PART;

    float best = INFINITY;
    int bi = 0x7fffffff;

    for (int q = t; q < NQ; q += NT) {
        float focal = 0.f, dnum = 0.f, dden = 0.f;
        float pYn = 0.f, pYd = 0.f, pXn = 0.f, pXd = 0.f;
        float tsum = 0.f, ysum = 0.f, xsum = 0.f;
        #pragma unroll
        for (int f = 0; f < NF; ++f) {
            int bf = b * NF + f;
            const float4* p = (const float4*)(part + (size_t)(bf * NQ + q) * 8);
            float4 pa = p[0], pbv = p[1];
            focal += pa.x; dnum += pa.y; dden += pa.z; pYn += pa.w;
            pYd += pbv.x; pXn += pbv.y; pXd += pbv.z;
            tsum += ws[WS_TSUM + bf];
            ysum += ws[WS_YSUM + bf];
            xsum += ws[WS_XSUM + bf];
        }
        float cost_mask = focal / (float)DTOT;
        float cost_dice = -(2.f * dnum + 1.f) / (dden + tsum + 1.f);
        float coefY = (2.f * pYn + 1.f) / (pYd + ysum + 1.f);
        float coefX = (2.f * pXn + 1.f) / (pXd + xsum + 1.f);
        float cost_proj = -0.5f * (coefY + coefX);

        float wsum = 0.f, cls = 0.f, cb = 0.f, cg = 0.f;
        #pragma unroll
        for (int f = 0; f < NF; ++f) {
            float wv = (tvalid[b * NF + f] != 0) ? 1.f : 0.f;
            wsum += wv;
            float lg = logits[(b * NF + f) * NQ + q];
            float p = sigmoid_fast(lg);
            float negc = 0.75f * p * p * (-__logf(1.f - p + 1e-8f));
            float posc = 0.25f * (1.f - p) * (1.f - p) * (-__logf(p + 1e-8f));
            cls += (posc - negc) * wv;

            const float* bx = boxes + (size_t)((b * NF + f) * NQ + q) * 4;
            const float* tbp = tbox + (b * NF + f) * 4;
            float cx = bx[0], cy = bx[1], bw = bx[2], bh = bx[3];
            float tcx = tbp[0], tcy = tbp[1], tbw = tbp[2], tbh = tbp[3];
            cb += fabsf(cx - tcx) + fabsf(cy - tcy) + fabsf(bw - tbw) + fabsf(bh - tbh);
            float sx1 = cx - 0.5f * bw, sy1 = cy - 0.5f * bh;
            float sx2 = cx + 0.5f * bw, sy2 = cy + 0.5f * bh;
            float tx1 = tcx - 0.5f * tbw, ty1 = tcy - 0.5f * tbh;
            float tx2 = tcx + 0.5f * tbw, ty2 = tcy + 0.5f * tbh;
            float a1 = (sx2 - sx1) * (sy2 - sy1), a2 = (tx2 - tx1) * (ty2 - ty1);
            float iw = fmaxf(fminf(sx2, tx2) - fmaxf(sx1, tx1), 0.f);
            float ih = fmaxf(fminf(sy2, ty2) - fmaxf(sy1, ty1), 0.f);
            float inter = iw * ih;
            float uni = a1 + a2 - inter;
            float iou = inter / uni;
            float cw = fmaxf(fmaxf(sx2, tx2) - fminf(sx1, tx1), 0.f);
            float chh = fmaxf(fmaxf(sy2, ty2) - fminf(sy1, ty1), 0.f);
            float areac = cw * chh;
            cg += -(iou - (areac - uni) / areac);
        }
        cls /= wsum;
        float c = cls + 0.125f * cb + 0.125f * cg + cost_mask + cost_dice + cost_proj;
        out[b * NQ + q] = c;
        if (c < best) { best = c; bi = q; }
    }

    #pragma unroll
    for (int off = 32; off > 0; off >>= 1) {
        float ov = __shfl_down(best, off, 64);
        int oi = __shfl_down(bi, off, 64);
        if (ov < best || (ov == best && oi < bi)) { best = ov; bi = oi; }
    }
    __shared__ float rv[4];
    __shared__ int ri[4];
    int wv = t >> 6, lane = t & 63;
    if (lane == 0) { rv[wv] = best; ri[wv] = bi; }
    __syncthreads();
    if (t == 0 && write_idx) {
        #pragma unroll
        for (int w = 1; w < 4; ++w) {
            if (rv[w] < best || (rv[w] == best && ri[w] < bi)) { best = rv[w]; bi = ri[w]; }
        }
        out[2 * NQ + b] = (float)bi;       // src_ind
        out[2 * NQ + 2 + b] = 0.f;         // tgt_ind
    }
}

extern "C" void kernel_launch(void* const* d_in, const int* in_sizes, int n_in,
                              void* d_out, int out_size, void* d_ws, size_t ws_size,
                              hipStream_t stream) {
    const float* logits = (const float*)d_in[0];
    const float* boxes  = (const float*)d_in[1];
    const float* masks  = (const float*)d_in[2];
    const float* tmask  = (const float*)d_in[3];
    const float* tbox   = (const float*)d_in[4];
    const int*   tvalid = (const int*)d_in[5];
    const unsigned char* vpad = (const unsigned char*)d_in[6];
    float* out = (float*)d_out;
    float* ws  = (float*)d_ws;

    targets_kernel<<<NBF, NT, 0, stream>>>(tmask, vpad, ws);
    partial_kernel<<<NBF * NQ, NT, 0, stream>>>(masks, ws, ws + WS_PART);
    int write_idx = (out_size >= 2 * NQ + 4) ? 1 : 0;
    final_kernel<<<2, NT, 0, stream>>>(logits, boxes, tbox, tvalid, ws, out, write_idx);
}